// Round 3
// baseline (1609.095 us; speedup 1.0000x reference)
//
#include <hip/hip_runtime.h>
#include <stdint.h>

// InvNet memory-bank loss, MI355X — R2 resubmit: latency-bound fix.
// k_main: 512 blocks (BN=64 cols x all 256 rows) -> 2 blocks/CU; 2-phase
//   pipeline: global_load_lds(f32 A, pre-swizzled src -> linear LDS ->
//   swizzled ds_read_b128) + reg-staged B (4 floats/thr, cvt on write),
//   both issued for t+1 before compute of t; one __syncthreads per iter.
//   Split sims = partial-K sums; boundary k-steps run MFMA twice with the
//   A frag masked lo/hi. Per-block exact top-6 per (split,row) packed as
//   u32 (monotonic-val 25b | local col 6b).
// k_merge: wave per (split,row): 3072 u32 cands -> u64 keys (tie = smaller
//   col, matching lax.top_k), dual independent insertion chains (halved
//   latency chain) + lane-local bitonic merge + cross-lane bitonic merge,
//   gather logp from stored sim, atomicAdd loss.
// ws: sim f32[256][32768] (32MB) | cand u32[10][256][512][6] (30MB) | sumexp[256].

typedef float f32x4 __attribute__((ext_vector_type(4)));
typedef __bf16 bf16x8 __attribute__((ext_vector_type(8)));
typedef unsigned short u16x8 __attribute__((ext_vector_type(8)));

#define NB 256
#define NC 32768
#define NF 2048
#define NSPLIT 10
#define SPLITW 205
#define BN 64
#define NBLK (NC / BN)   // 512
#define NKSTEP 64
#define INV_BETA 20.0f

__device__ __forceinline__ unsigned short f2bf(float f) {
  uint32_t u = __float_as_uint(f);
  return (unsigned short)((u + 0x7FFFu + ((u >> 16) & 1u)) >> 16);  // RNE
}
__device__ __forceinline__ bf16x8 asbf(u16x8 v) {
  union { u16x8 u; bf16x8 b; } x; x.u = v; return x.b;
}

#define GLDS16(g, p) __builtin_amdgcn_global_load_lds(                         \
    (const __attribute__((address_space(1))) unsigned int*)(g),                \
    (__attribute__((address_space(3))) unsigned int*)(p), 16, 0, 0)

__global__ __launch_bounds__(256)
void k_zero(float* __restrict__ sumexp, float* __restrict__ out) {
  int t = threadIdx.x;
  if (t < NB) sumexp[t] = 0.f;
  if (t == 0) out[0] = 0.f;
}

__global__ __launch_bounds__(512, 4)
void k_main(const float* __restrict__ inp, const float* __restrict__ em,
            float* __restrict__ sim, uint32_t* __restrict__ cand,
            float* __restrict__ sumexp) {
  // A: 256 rows x 32 k, f32, as 32 chunks of (8 rows x 32 f32 = 1KB).
  // Within a chunk-row, 16B granule g stored at slot g^rr (bank spread).
  __shared__ float Af[2][8192];            // 2 x 32 KB
  // B: 64 rows x 32 k, bf16. Row = 4 x 16B units; unit u at slot u^((row>>1)&3).
  __shared__ unsigned short Bh[2][2048];   // 2 x 4 KB

  const int t  = threadIdx.x;
  const int l  = t & 63;
  const int w  = t >> 6;       // wave 0..7 owns rows [w*32, w*32+32)
  const int li = l & 15, lg = l >> 4;
  const int bx = blockIdx.x;
  const int c0 = bx * BN;

  // A-glds per-lane source coords (pre-swizzled so linear LDS = swizzled layout)
  const int arr = l >> 3;            // row within 8-row chunk
  const int ag  = (l & 7) ^ arr;     // source 16B granule index
  // B staging coords: thread covers row br, floats bg*4..+3
  const int br  = t >> 3, bg = t & 7;
  const int bus = (bg >> 1) ^ ((br >> 1) & 3);
  const int bh2 = bg & 1;

  const f32x4 Z4 = {0.f, 0.f, 0.f, 0.f};
  f32x4 accT[2][4], accS[2][4];
  #pragma unroll
  for (int m = 0; m < 2; m++)
    #pragma unroll
    for (int n = 0; n < 4; n++) { accT[m][n] = Z4; accS[m][n] = Z4; }

  auto issueA = [&](int bb, int tt) {
    #pragma unroll
    for (int j = 0; j < 4; j++) {
      const int c = w * 4 + j;                       // chunk 0..31
      const float* g = inp + (size_t)(c * 8 + arr) * NF + tt * 32 + ag * 4;
      GLDS16(g, &Af[bb][c * 256]);
    }
  };

  auto finalize = [&](int s) {
    #pragma unroll
    for (int m = 0; m < 2; m++)
      #pragma unroll
      for (int n = 0; n < 4; n++) accT[m][n] += accS[m][n];
    #pragma unroll
    for (int m = 0; m < 2; m++) {
      #pragma unroll
      for (int j = 0; j < 4; j++) {
        uint32_t p[4];
        #pragma unroll
        for (int n = 0; n < 4; n++) {
          uint32_t u = __float_as_uint(accS[m][n][j]);
          u ^= (uint32_t)(((int32_t)u) >> 31) | 0x80000000u;   // monotonic map
          p[n] = (u & 0xFFFFFF80u) | (uint32_t)(n * 16 + li);  // val25|col6
        }
        uint32_t res[6];
        #pragma unroll
        for (int r = 0; r < 6; r++) {
          uint32_t mx = p[0];
          #pragma unroll
          for (int n = 1; n < 4; n++) mx = mx > p[n] ? mx : p[n];
          #pragma unroll
          for (int d = 1; d < 16; d <<= 1) {
            uint32_t o = __shfl_xor(mx, d);       // within 16-lane row group
            mx = mx > o ? mx : o;
          }
          res[r] = mx;
          #pragma unroll
          for (int n = 0; n < 4; n++) p[n] = (p[n] == mx) ? 0u : p[n];
        }
        if (li == 0) {
          const int rowg = w * 32 + m * 16 + lg * 4 + j;
          uint32_t* dst = cand + ((size_t)(s * NB + rowg) * NBLK + bx) * 6;
          #pragma unroll
          for (int r = 0; r < 6; r++) dst[r] = res[r];
        }
      }
      #pragma unroll
      for (int n = 0; n < 4; n++) accS[m][n] = Z4;
    }
  };

  auto step = [&](int tt, int cb, int nb) {
    f32x4 bv;
    const bool pre = (tt + 1 < NKSTEP);
    if (pre) {
      issueA(nb, tt + 1);                                          // async -> LDS
      bv = *(const f32x4*)(em + (size_t)(c0 + br) * NF + (tt + 1) * 32 + bg * 4);
    }
    // A frags: two swizzled b128 f32 reads, cvt to bf16 in regs
    u16x8 af[2];
    #pragma unroll
    for (int m = 0; m < 2; m++) {
      const int chunk = w * 4 + m * 2 + (li >> 3);
      const int rr = li & 7;
      const float* bp = &Af[cb][chunk * 256 + rr * 32];
      f32x4 x0 = *(const f32x4*)(bp + (((lg << 1)    ) ^ rr) * 4);
      f32x4 x1 = *(const f32x4*)(bp + (((lg << 1) | 1) ^ rr) * 4);
      u16x8 r;
      r[0] = f2bf(x0[0]); r[1] = f2bf(x0[1]); r[2] = f2bf(x0[2]); r[3] = f2bf(x0[3]);
      r[4] = f2bf(x1[0]); r[5] = f2bf(x1[1]); r[6] = f2bf(x1[2]); r[7] = f2bf(x1[3]);
      af[m] = r;
    }
    u16x8 bfv[4];
    #pragma unroll
    for (int n = 0; n < 4; n++) {
      const int rowp = n * 16 + li;
      const int sl = lg ^ ((rowp >> 1) & 3);
      bfv[n] = *(const u16x8*)&Bh[cb][rowp * 32 + sl * 8];
    }
    const int k0 = tt * 32;
    const int s0 = k0 / SPLITW, s1 = (k0 + 31) / SPLITW;
    if (s1 > s0) {   // split boundary inside this k-step (9 of 64 iters)
      const int thr = s1 * SPLITW - k0;  // 1..31
      u16x8 am[2];
      #pragma unroll
      for (int m = 0; m < 2; m++)
        #pragma unroll
        for (int e = 0; e < 8; e++)
          am[m][e] = (lg * 8 + e) < thr ? af[m][e] : (unsigned short)0;
      #pragma unroll
      for (int m = 0; m < 2; m++)
        #pragma unroll
        for (int n = 0; n < 4; n++)
          accS[m][n] = __builtin_amdgcn_mfma_f32_16x16x32_bf16(
              asbf(am[m]), asbf(bfv[n]), accS[m][n], 0, 0, 0);
      finalize(s0);
      #pragma unroll
      for (int m = 0; m < 2; m++)
        #pragma unroll
        for (int e = 0; e < 8; e++)
          am[m][e] = (lg * 8 + e) < thr ? (unsigned short)0 : af[m][e];
      #pragma unroll
      for (int m = 0; m < 2; m++)
        #pragma unroll
        for (int n = 0; n < 4; n++)
          accS[m][n] = __builtin_amdgcn_mfma_f32_16x16x32_bf16(
              asbf(am[m]), asbf(bfv[n]), accS[m][n], 0, 0, 0);
    } else {
      #pragma unroll
      for (int m = 0; m < 2; m++)
        #pragma unroll
        for (int n = 0; n < 4; n++)
          accS[m][n] = __builtin_amdgcn_mfma_f32_16x16x32_bf16(
              asbf(af[m]), asbf(bfv[n]), accS[m][n], 0, 0, 0);
    }
    if (pre) {   // B cvt+write lands in buf[nb] before the barrier
      ushort4 hh;
      hh.x = f2bf(bv[0]); hh.y = f2bf(bv[1]); hh.z = f2bf(bv[2]); hh.w = f2bf(bv[3]);
      *(ushort4*)&Bh[nb][br * 32 + bus * 8 + bh2 * 4] = hh;
    }
    __syncthreads();   // drains glds (vmcnt) + ds_write, flips buffers
  };

  // prologue: stage tile 0
  {
    issueA(0, 0);
    f32x4 bv = *(const f32x4*)(em + (size_t)(c0 + br) * NF + bg * 4);
    ushort4 hh;
    hh.x = f2bf(bv[0]); hh.y = f2bf(bv[1]); hh.z = f2bf(bv[2]); hh.w = f2bf(bv[3]);
    *(ushort4*)&Bh[0][br * 32 + bus * 8 + bh2 * 4] = hh;
    __syncthreads();
  }
  for (int tt = 0; tt < NKSTEP; tt += 2) { step(tt, 0, 1); step(tt + 1, 1, 0); }
  finalize(NSPLIT - 1);

  // epilogue: scaled sim write + per-row sumexp partials (|sim|<=20.5)
  #pragma unroll
  for (int m = 0; m < 2; m++) {
    #pragma unroll
    for (int j = 0; j < 4; j++) {
      const int rowg = w * 32 + m * 16 + lg * 4 + j;
      float se = 0.f;
      #pragma unroll
      for (int n = 0; n < 4; n++) {
        float v = accT[m][n][j] * INV_BETA;
        sim[(size_t)rowg * NC + c0 + n * 16 + li] = v;
        se += __expf(v);
      }
      #pragma unroll
      for (int d = 1; d < 16; d <<= 1) se += __shfl_xor(se, d);
      if (li == 0) atomicAdd(&sumexp[rowg], se);
    }
  }
}

__device__ __forceinline__ void casd(unsigned long long& a, unsigned long long& b) {
  unsigned long long mx = a > b ? a : b;
  unsigned long long mn = a > b ? b : a;
  a = mx; b = mn;
}

// merge two descending sorted-8 lists (a, b) -> a = top-8, descending
__device__ __forceinline__ void merge8(unsigned long long* a,
                                       const unsigned long long* b) {
  unsigned long long hi[8];
  #pragma unroll
  for (int i = 0; i < 8; i++) {
    unsigned long long x = a[i], y = b[7 - i];
    hi[i] = x > y ? x : y;
  }
  casd(hi[0], hi[4]); casd(hi[1], hi[5]); casd(hi[2], hi[6]); casd(hi[3], hi[7]);
  casd(hi[0], hi[2]); casd(hi[1], hi[3]); casd(hi[4], hi[6]); casd(hi[5], hi[7]);
  casd(hi[0], hi[1]); casd(hi[2], hi[3]); casd(hi[4], hi[5]); casd(hi[6], hi[7]);
  #pragma unroll
  for (int i = 0; i < 8; i++) a[i] = hi[i];
}

__global__ __launch_bounds__(64)
void k_merge(const uint32_t* __restrict__ cand, const float* __restrict__ sim,
             const float* __restrict__ sumexp, const int* __restrict__ tgt,
             float* __restrict__ out) {
  const int s = blockIdx.x >> 8;
  const int b = blockIdx.x & 255;
  const int l = threadIdx.x;

  const uint32_t* src = cand + (size_t)(s * NB + b) * (NBLK * 6);
  unsigned long long ta[8], tb[8];
  #pragma unroll
  for (int i = 0; i < 8; i++) { ta[i] = 0ull; tb[i] = 0ull; }

  // two independent insertion chains (even/odd i) to halve the serial
  // dependency in this latency-bound single-wave kernel
  #pragma unroll 6
  for (int i = 0; i < 48; i += 2) {
    const int i0 = l + i * 64, i1 = l + (i + 1) * 64;
    const uint32_t e0 = src[i0], e1 = src[i1];
    const uint32_t c0g = (uint32_t)(i0 / 6) * 64u + (e0 & 63u);
    const uint32_t c1g = (uint32_t)(i1 / 6) * 64u + (e1 & 63u);
    unsigned long long v0 = ((unsigned long long)(e0 & 0xFFFFFF80u) << 32)
                          | (unsigned long long)(0xFFFFu ^ c0g);
    unsigned long long v1 = ((unsigned long long)(e1 & 0xFFFFFF80u) << 32)
                          | (unsigned long long)(0xFFFFu ^ c1g);
    #pragma unroll
    for (int k = 0; k < 8; k++) {
      if (v0 > ta[k]) { unsigned long long tmp = ta[k]; ta[k] = v0; v0 = tmp; }
      if (v1 > tb[k]) { unsigned long long tmp = tb[k]; tb[k] = v1; v1 = tmp; }
    }
  }
  merge8(ta, tb);   // lane-local top-8 of this lane's 48 candidates

  // cross-lane bitonic all-reduce: every lane ends with global top-8
  #pragma unroll
  for (int d = 1; d < 64; d <<= 1) {
    unsigned long long o[8];
    #pragma unroll
    for (int i = 0; i < 8; i++) o[i] = __shfl_xor(ta[i], d);
    merge8(ta, o);
  }
  if (l == 0) {
    const int tg = tgt[b];
    const float lz = logf(sumexp[b]);
    float acc = 0.f; int cnt = 0;
    #pragma unroll
    for (int r = 0; r < 6; r++) {
      const int col = (int)(((unsigned)(ta[r] & 0xFFFFull)) ^ 0xFFFFu);
      if (col != tg) { acc += sim[(size_t)b * NC + col]; cnt++; }
    }
    const float simt = sim[(size_t)b * NC + tg];
    const float contrib = (simt - lz) + (acc - (float)cnt * lz) * (1.0f / 6.0f);
    atomicAdd(out, -contrib * (1.0f / (NSPLIT * NB)));
  }
}

extern "C" void kernel_launch(void* const* d_in, const int* in_sizes, int n_in,
                              void* d_out, int out_size, void* d_ws, size_t ws_size,
                              hipStream_t stream) {
  const float* inp = (const float*)d_in[0];
  const float* em  = (const float*)d_in[1];
  const int*   tgt = (const int*)d_in[2];
  float* out = (float*)d_out;

  char* ws = (char*)d_ws;
  float* sim = (float*)ws;                                          // 32 MB
  uint32_t* cand = (uint32_t*)(ws + (size_t)NB * NC * 4);           // 30 MB
  float* sumexp = (float*)(ws + (size_t)NB * NC * 4 +
                           (size_t)NSPLIT * NB * NBLK * 6 * 4);

  k_zero<<<1, 256, 0, stream>>>(sumexp, out);
  k_main<<<NBLK, 512, 0, stream>>>(inp, em, sim, cand, sumexp);
  k_merge<<<NSPLIT * NB, 64, 0, stream>>>(cand, sim, sumexp, tgt, out);
}

// Round 4
// 837.856 us; speedup vs baseline: 1.9205x; 1.9205x over previous
//
#include <hip/hip_runtime.h>
#include <stdint.h>

// InvNet memory-bank loss, MI355X — R4: de-lambda k_main (R3 scratch-spill fix)
//   + two-level candidate merge.
// k_main: 512 blocks (BN=64 cols x all 256 rows), 2 blocks/CU; pipeline:
//   global_load_lds(f32 A, pre-swizzled src -> linear LDS -> swizzled
//   ds_read_b128) + reg-staged B (cvt on write), both issued for t+1 before
//   compute of t; one __syncthreads per K-step. Split sims = partial-K sums;
//   boundary steps run MFMA twice with lo/hi-masked A frag. Exact per-block
//   top-6 per (split,row) packed u32 (monotonic-val 25b | local col 6b).
//   ALL inner code macro-expanded (no lambdas) so acc arrays stay in VGPRs.
// k_m1: 20480 single-wave blocks: (split,row,group-of-64-colblocks) -> merge
//   384 cands -> top-6 u64 keys (tie = smaller col, like lax.top_k).
// k_m2: 2560 single-wave blocks: merge 48 survivors, gather logp, atomicAdd.
// ws: sim f32[256][32768] 32MB | cand u32[10][256][512][6] 30MB |
//     part u64[10][256][8][6] 0.94MB | sumexp f32[256].

typedef float f32x4 __attribute__((ext_vector_type(4)));
typedef __bf16 bf16x8 __attribute__((ext_vector_type(8)));
typedef unsigned short u16x8 __attribute__((ext_vector_type(8)));

#define NB 256
#define NC 32768
#define NF 2048
#define NSPLIT 10
#define SPLITW 205
#define BN 64
#define NBLK (NC / BN)   // 512
#define NKSTEP 64
#define INV_BETA 20.0f
#define UNRL _Pragma("unroll")

__device__ __forceinline__ unsigned short f2bf(float f) {
  uint32_t u = __float_as_uint(f);
  return (unsigned short)((u + 0x7FFFu + ((u >> 16) & 1u)) >> 16);  // RNE
}
__device__ __forceinline__ bf16x8 asbf(u16x8 v) {
  union { u16x8 u; bf16x8 b; } x; x.u = v; return x.b;
}

#define GLDS16(g, p) __builtin_amdgcn_global_load_lds(                         \
    (const __attribute__((address_space(1))) unsigned int*)(g),                \
    (__attribute__((address_space(3))) unsigned int*)(p), 16, 0, 0)

__global__ __launch_bounds__(256)
void k_zero(float* __restrict__ sumexp, float* __restrict__ out) {
  int t = threadIdx.x;
  if (t < NB) sumexp[t] = 0.f;
  if (t == 0) out[0] = 0.f;
}

// ---- k_main macros (no lambdas: keep acc arrays SROA-able into VGPRs) ----

#define ISSUE_A(BB, TT) do {                                                   \
  UNRL for (int j_ = 0; j_ < 4; j_++) {                                        \
    const int c_ = w * 4 + j_;                                                 \
    const float* g_ = inp + (size_t)(c_ * 8 + arr) * NF + (TT) * 32 + ag * 4;  \
    GLDS16(g_, &Af[BB][c_ * 256]);                                             \
  }                                                                            \
} while (0)

#define FINALIZE(S) do {                                                       \
  UNRL for (int m_ = 0; m_ < 2; m_++)                                          \
    UNRL for (int n_ = 0; n_ < 4; n_++) accT[m_][n_] += accS[m_][n_];          \
  UNRL for (int m_ = 0; m_ < 2; m_++) {                                        \
    UNRL for (int j_ = 0; j_ < 4; j_++) {                                      \
      uint32_t p_[4];                                                          \
      UNRL for (int n_ = 0; n_ < 4; n_++) {                                    \
        uint32_t u_ = __float_as_uint(accS[m_][n_][j_]);                       \
        u_ ^= (uint32_t)(((int32_t)u_) >> 31) | 0x80000000u;                   \
        p_[n_] = (u_ & 0xFFFFFF80u) | (uint32_t)(n_ * 16 + li);                \
      }                                                                        \
      uint32_t res_[6];                                                        \
      UNRL for (int r_ = 0; r_ < 6; r_++) {                                    \
        uint32_t mx_ = p_[0];                                                  \
        UNRL for (int n_ = 1; n_ < 4; n_++) mx_ = mx_ > p_[n_] ? mx_ : p_[n_]; \
        UNRL for (int d_ = 1; d_ < 16; d_ <<= 1) {                             \
          uint32_t o_ = __shfl_xor(mx_, d_);                                   \
          mx_ = mx_ > o_ ? mx_ : o_;                                           \
        }                                                                      \
        res_[r_] = mx_;                                                        \
        UNRL for (int n_ = 0; n_ < 4; n_++)                                    \
          p_[n_] = (p_[n_] == mx_) ? 0u : p_[n_];                              \
      }                                                                        \
      if (li == 0) {                                                           \
        const int rowg_ = w * 32 + m_ * 16 + lg * 4 + j_;                      \
        uint32_t* dst_ = cand + ((size_t)((S) * NB + rowg_) * NBLK + bx) * 6;  \
        UNRL for (int r_ = 0; r_ < 6; r_++) dst_[r_] = res_[r_];               \
      }                                                                        \
    }                                                                          \
    UNRL for (int n_ = 0; n_ < 4; n_++) accS[m_][n_] = Z4;                     \
  }                                                                            \
} while (0)

#define MFMA_ALL(AF) do {                                                      \
  UNRL for (int m_ = 0; m_ < 2; m_++)                                          \
    UNRL for (int n_ = 0; n_ < 4; n_++)                                        \
      accS[m_][n_] = __builtin_amdgcn_mfma_f32_16x16x32_bf16(                  \
          asbf((AF)[m_]), asbf(bfv_[n_]), accS[m_][n_], 0, 0, 0);              \
} while (0)

#define STEP(TT, CB, NBUF, PRE) do {                                           \
  f32x4 bv_ = {0.f, 0.f, 0.f, 0.f};                                            \
  if (PRE) {                                                                   \
    ISSUE_A(NBUF, (TT) + 1);                                                   \
    bv_ = *(const f32x4*)(em + (size_t)(c0 + br) * NF + ((TT) + 1) * 32 + bg * 4); \
  }                                                                            \
  u16x8 af_[2];                                                                \
  UNRL for (int m_ = 0; m_ < 2; m_++) {                                        \
    const int chunk_ = w * 4 + m_ * 2 + (li >> 3);                             \
    const int rr_ = li & 7;                                                    \
    const float* bp_ = &Af[CB][chunk_ * 256 + rr_ * 32];                       \
    f32x4 x0_ = *(const f32x4*)(bp_ + (((lg << 1)) ^ rr_) * 4);                \
    f32x4 x1_ = *(const f32x4*)(bp_ + (((lg << 1) | 1) ^ rr_) * 4);            \
    af_[m_][0] = f2bf(x0_[0]); af_[m_][1] = f2bf(x0_[1]);                      \
    af_[m_][2] = f2bf(x0_[2]); af_[m_][3] = f2bf(x0_[3]);                      \
    af_[m_][4] = f2bf(x1_[0]); af_[m_][5] = f2bf(x1_[1]);                      \
    af_[m_][6] = f2bf(x1_[2]); af_[m_][7] = f2bf(x1_[3]);                      \
  }                                                                            \
  u16x8 bfv_[4];                                                               \
  UNRL for (int n_ = 0; n_ < 4; n_++) {                                        \
    const int rowp_ = n_ * 16 + li;                                            \
    const int sl_ = lg ^ ((rowp_ >> 1) & 3);                                   \
    bfv_[n_] = *(const u16x8*)&Bh[CB][rowp_ * 32 + sl_ * 8];                   \
  }                                                                            \
  const int k0_ = (TT) * 32;                                                   \
  const int s0_ = k0_ / SPLITW, s1_ = (k0_ + 31) / SPLITW;                     \
  if (s1_ > s0_) {                                                             \
    const int thr_ = s1_ * SPLITW - k0_;                                       \
    u16x8 am_[2];                                                              \
    UNRL for (int m_ = 0; m_ < 2; m_++)                                        \
      UNRL for (int e_ = 0; e_ < 8; e_++)                                      \
        am_[m_][e_] = (lg * 8 + e_) < thr_ ? af_[m_][e_] : (unsigned short)0;  \
    MFMA_ALL(am_);                                                             \
    FINALIZE(s0_);                                                             \
    UNRL for (int m_ = 0; m_ < 2; m_++)                                        \
      UNRL for (int e_ = 0; e_ < 8; e_++)                                      \
        am_[m_][e_] = (lg * 8 + e_) < thr_ ? (unsigned short)0 : af_[m_][e_];  \
    MFMA_ALL(am_);                                                             \
  } else {                                                                     \
    MFMA_ALL(af_);                                                             \
  }                                                                            \
  if (PRE) {                                                                   \
    ushort4 hh_;                                                               \
    hh_.x = f2bf(bv_[0]); hh_.y = f2bf(bv_[1]);                                \
    hh_.z = f2bf(bv_[2]); hh_.w = f2bf(bv_[3]);                                \
    *(ushort4*)&Bh[NBUF][br * 32 + bus * 8 + bh2 * 4] = hh_;                   \
  }                                                                            \
  __syncthreads();                                                             \
} while (0)

__global__ __launch_bounds__(512, 4)
void k_main(const float* __restrict__ inp, const float* __restrict__ em,
            float* __restrict__ sim, uint32_t* __restrict__ cand,
            float* __restrict__ sumexp) {
  // A: 32 chunks of (8 rows x 32 f32); granule g of row rr at slot g^rr.
  __shared__ float Af[2][8192];            // 2 x 32 KB
  // B: 64 rows x 32 bf16; 16B unit u of row at slot u^((row>>1)&3).
  __shared__ unsigned short Bh[2][2048];   // 2 x 4 KB

  const int t  = threadIdx.x;
  const int l  = t & 63;
  const int w  = t >> 6;       // wave 0..7 owns rows [w*32, w*32+32)
  const int li = l & 15, lg = l >> 4;
  const int bx = blockIdx.x;
  const int c0 = bx * BN;

  const int arr = l >> 3;            // A-glds: row within 8-row chunk
  const int ag  = (l & 7) ^ arr;     // pre-swizzled source granule
  const int br  = t >> 3, bg = t & 7;          // B staging coords
  const int bus = (bg >> 1) ^ ((br >> 1) & 3);
  const int bh2 = bg & 1;

  const f32x4 Z4 = {0.f, 0.f, 0.f, 0.f};
  f32x4 accT[2][4], accS[2][4];
  UNRL for (int m = 0; m < 2; m++)
    UNRL for (int n = 0; n < 4; n++) { accT[m][n] = Z4; accS[m][n] = Z4; }

  // prologue: stage tile 0 into buffer 0
  {
    ISSUE_A(0, 0);
    f32x4 bv = *(const f32x4*)(em + (size_t)(c0 + br) * NF + bg * 4);
    ushort4 hh;
    hh.x = f2bf(bv[0]); hh.y = f2bf(bv[1]); hh.z = f2bf(bv[2]); hh.w = f2bf(bv[3]);
    *(ushort4*)&Bh[0][br * 32 + bus * 8 + bh2 * 4] = hh;
    __syncthreads();
  }
  for (int tt2 = 0; tt2 < 31; ++tt2) {
    STEP(2 * tt2, 0, 1, 1);
    STEP(2 * tt2 + 1, 1, 0, 1);
  }
  STEP(62, 0, 1, 1);
  STEP(63, 1, 0, 0);
  FINALIZE(NSPLIT - 1);

  // epilogue: scaled sim write + per-row sumexp partials (|sim|<=20.5)
  UNRL for (int m = 0; m < 2; m++) {
    UNRL for (int j = 0; j < 4; j++) {
      const int rowg = w * 32 + m * 16 + lg * 4 + j;
      float se = 0.f;
      UNRL for (int n = 0; n < 4; n++) {
        float v = accT[m][n][j] * INV_BETA;
        sim[(size_t)rowg * NC + c0 + n * 16 + li] = v;
        se += __expf(v);
      }
      UNRL for (int d = 1; d < 16; d <<= 1) se += __shfl_xor(se, d);
      if (li == 0) atomicAdd(&sumexp[rowg], se);
    }
  }
}

__device__ __forceinline__ void casd(unsigned long long& a, unsigned long long& b) {
  unsigned long long mx = a > b ? a : b;
  unsigned long long mn = a > b ? b : a;
  a = mx; b = mn;
}

// merge two descending sorted-8 lists -> a = top-8 descending
__device__ __forceinline__ void merge8(unsigned long long* a,
                                       const unsigned long long* b) {
  unsigned long long hi[8];
  UNRL for (int i = 0; i < 8; i++) {
    unsigned long long x = a[i], y = b[7 - i];
    hi[i] = x > y ? x : y;
  }
  casd(hi[0], hi[4]); casd(hi[1], hi[5]); casd(hi[2], hi[6]); casd(hi[3], hi[7]);
  casd(hi[0], hi[2]); casd(hi[1], hi[3]); casd(hi[4], hi[6]); casd(hi[5], hi[7]);
  casd(hi[0], hi[1]); casd(hi[2], hi[3]); casd(hi[4], hi[5]); casd(hi[6], hi[7]);
  UNRL for (int i = 0; i < 8; i++) a[i] = hi[i];
}

// level 1: (split, row, group of 64 col-blocks) -> top-6 of 384 candidates
__global__ __launch_bounds__(64)
void k_m1(const uint32_t* __restrict__ cand,
          unsigned long long* __restrict__ part) {
  const int bx = blockIdx.x;           // 20480 = 10 * 256 * 8
  const int s = bx >> 11;
  const int b = (bx >> 3) & 255;
  const int g = bx & 7;
  const int l = threadIdx.x;

  const uint32_t* src = cand + ((size_t)(s * NB + b) * NBLK + g * 64) * 6;
  unsigned long long t8[8];
  UNRL for (int i = 0; i < 8; i++) t8[i] = 0ull;

  UNRL for (int i = 0; i < 6; i++) {
    const int idx = l + i * 64;                       // 0..383, coalesced
    const uint32_t e = src[idx];
    const uint32_t colg = (uint32_t)(g * 64 + idx / 6) * 64u + (e & 63u);
    unsigned long long v = ((unsigned long long)(e & 0xFFFFFF80u) << 32)
                         | (unsigned long long)(0xFFFFu ^ colg);
    UNRL for (int k = 0; k < 8; k++) {
      if (v > t8[k]) { unsigned long long tmp = t8[k]; t8[k] = v; v = tmp; }
    }
  }
  UNRL for (int d = 1; d < 64; d <<= 1) {
    unsigned long long o[8];
    UNRL for (int i = 0; i < 8; i++) o[i] = __shfl_xor(t8[i], d);
    merge8(t8, o);
  }
  if (l == 0) {
    unsigned long long* dst = part + ((size_t)(s * NB + b) * 8 + g) * 6;
    UNRL for (int r = 0; r < 6; r++) dst[r] = t8[r];
  }
}

// level 2: merge 48 survivors, gather logp from sim, accumulate loss
__global__ __launch_bounds__(64)
void k_m2(const unsigned long long* __restrict__ part,
          const float* __restrict__ sim, const float* __restrict__ sumexp,
          const int* __restrict__ tgt, float* __restrict__ out) {
  const int s = blockIdx.x >> 8;
  const int b = blockIdx.x & 255;
  const int l = threadIdx.x;

  unsigned long long t8[8];
  UNRL for (int i = 0; i < 8; i++) t8[i] = 0ull;
  t8[0] = (l < 48) ? part[(size_t)(s * NB + b) * 48 + l] : 0ull;

  UNRL for (int d = 1; d < 64; d <<= 1) {
    unsigned long long o[8];
    UNRL for (int i = 0; i < 8; i++) o[i] = __shfl_xor(t8[i], d);
    merge8(t8, o);
  }
  if (l == 0) {
    const int tg = tgt[b];
    const float lz = logf(sumexp[b]);
    float acc = 0.f; int cnt = 0;
    UNRL for (int r = 0; r < 6; r++) {
      const int col = (int)(((unsigned)(t8[r] & 0xFFFFull)) ^ 0xFFFFu);
      if (col != tg) { acc += sim[(size_t)b * NC + col]; cnt++; }
    }
    const float simt = sim[(size_t)b * NC + tg];
    const float contrib = (simt - lz) + (acc - (float)cnt * lz) * (1.0f / 6.0f);
    atomicAdd(out, -contrib * (1.0f / (NSPLIT * NB)));
  }
}

extern "C" void kernel_launch(void* const* d_in, const int* in_sizes, int n_in,
                              void* d_out, int out_size, void* d_ws, size_t ws_size,
                              hipStream_t stream) {
  const float* inp = (const float*)d_in[0];
  const float* em  = (const float*)d_in[1];
  const int*   tgt = (const int*)d_in[2];
  float* out = (float*)d_out;

  char* ws = (char*)d_ws;
  float* sim = (float*)ws;                                          // 32 MB
  size_t off = (size_t)NB * NC * 4;
  uint32_t* cand = (uint32_t*)(ws + off);                           // 30 MB
  off += (size_t)NSPLIT * NB * NBLK * 6 * 4;
  unsigned long long* part = (unsigned long long*)(ws + off);       // 0.94 MB
  off += (size_t)NSPLIT * NB * 8 * 6 * 8;
  float* sumexp = (float*)(ws + off);

  k_zero<<<1, 256, 0, stream>>>(sumexp, out);
  k_main<<<NBLK, 512, 0, stream>>>(inp, em, sim, cand, sumexp);
  k_m1<<<NSPLIT * NB * 8, 64, 0, stream>>>(cand, part);
  k_m2<<<NSPLIT * NB, 64, 0, stream>>>(part, sim, sumexp, tgt, out);
}

// Round 7
// 801.325 us; speedup vs baseline: 2.0080x; 1.0456x over previous
//
#include <hip/hip_runtime.h>
#include <stdint.h>

// InvNet memory-bank loss, MI355X — R6 (= R5 design, unroll 4->2 anti-spill).
// k_cvtA: inp f32[256][2048] -> bf16 (1MB, L2-resident on every XCD).
// k_main: 4096 single-wave blocks (rg=bx>>9: 8 row-groups x 32 rows;
//   cb=bx&511: 512 col-blocks x 64 cols). XCD = bx%8 = cb%8, so the 8
//   row-group sharers of a B col-tile run on the SAME XCD -> B re-reads
//   are L2 hits. Per K-step (32): A frags direct global bf16 loads,
//   B frags direct global f32 loads + cvt, 8 MFMA. NO LDS, NO
//   __syncthreads -> no vmcnt(0) barrier drains; unroll-2 lets loads run
//   one step ahead within the 128-VGPR cap; 4 waves/SIMD hide the rest.
//   Split sims = partial-K sums; boundary steps (9/64) run MFMA twice
//   with lo/hi-masked A frag; exact per-block top-6 per (split,row)
//   packed u32 (val25|col6).
// k_m1/k_m2: two-level candidate merge (u64 keys, tie = smaller col,
//   matching lax.top_k), gather logp from sim, atomicAdd loss.
// ws: sim f32[256][32768] 32MB | cand u32[10][256][512][6] 30MB |
//     part u64[10][256][8][6] 0.94MB | sumexp f32[256] | A_bf16 1MB. ~64MB.

typedef float f32x4 __attribute__((ext_vector_type(4)));
typedef __bf16 bf16x8 __attribute__((ext_vector_type(8)));
typedef unsigned short u16x8 __attribute__((ext_vector_type(8)));

#define NB 256
#define NC 32768
#define NF 2048
#define NSPLIT 10
#define SPLITW 205
#define WM 32
#define WN 64
#define NBLK (NC / WN)   // 512
#define NKSTEP 64
#define INV_BETA 20.0f
#define UNRL _Pragma("unroll")

__device__ __forceinline__ bf16x8 asbf(u16x8 v) {
  union { u16x8 u; bf16x8 b; } x; x.u = v; return x.b;
}

__global__ __launch_bounds__(256)
void k_zero(float* __restrict__ sumexp, float* __restrict__ out) {
  int t = threadIdx.x;
  if (t < NB) sumexp[t] = 0.f;
  if (t == 0) out[0] = 0.f;
}

__global__ __launch_bounds__(256)
void k_cvtA(const float* __restrict__ inp, unsigned short* __restrict__ abf) {
  const int idx = (blockIdx.x * 256 + threadIdx.x) * 8;
  f32x4 v0 = *(const f32x4*)(inp + idx);
  f32x4 v1 = *(const f32x4*)(inp + idx + 4);
  union { bf16x8 b; u16x8 u; } cv;
  UNRL for (int e = 0; e < 4; e++) cv.b[e] = (__bf16)v0[e];
  UNRL for (int e = 0; e < 4; e++) cv.b[4 + e] = (__bf16)v1[e];
  *(u16x8*)(abf + idx) = cv.u;
}

// ---- k_main macros (macro-expanded: keep acc arrays in VGPRs) ----

#define FINALIZE(S) do {                                                       \
  UNRL for (int m_ = 0; m_ < 2; m_++)                                          \
    UNRL for (int n_ = 0; n_ < 4; n_++) accT[m_][n_] += accS[m_][n_];          \
  UNRL for (int m_ = 0; m_ < 2; m_++) {                                        \
    UNRL for (int j_ = 0; j_ < 4; j_++) {                                      \
      uint32_t p_[4];                                                          \
      UNRL for (int n_ = 0; n_ < 4; n_++) {                                    \
        uint32_t u_ = __float_as_uint(accS[m_][n_][j_]);                       \
        u_ ^= (uint32_t)(((int32_t)u_) >> 31) | 0x80000000u;                   \
        p_[n_] = (u_ & 0xFFFFFF80u) | (uint32_t)(n_ * 16 + li);                \
      }                                                                        \
      uint32_t res_[6];                                                        \
      UNRL for (int r_ = 0; r_ < 6; r_++) {                                    \
        uint32_t mx_ = p_[0];                                                  \
        UNRL for (int n_ = 1; n_ < 4; n_++) mx_ = mx_ > p_[n_] ? mx_ : p_[n_]; \
        UNRL for (int d_ = 1; d_ < 16; d_ <<= 1) {                             \
          uint32_t o_ = __shfl_xor(mx_, d_);                                   \
          mx_ = mx_ > o_ ? mx_ : o_;                                           \
        }                                                                      \
        res_[r_] = mx_;                                                        \
        UNRL for (int n_ = 0; n_ < 4; n_++)                                    \
          p_[n_] = (p_[n_] == mx_) ? 0u : p_[n_];                              \
      }                                                                        \
      if (li == 0) {                                                           \
        const int rowg_ = r0 + m_ * 16 + lg * 4 + j_;                          \
        uint32_t* dst_ = cand + ((size_t)((S) * NB + rowg_) * NBLK + cb) * 6;  \
        UNRL for (int r_ = 0; r_ < 6; r_++) dst_[r_] = res_[r_];               \
      }                                                                        \
    }                                                                          \
    UNRL for (int n_ = 0; n_ < 4; n_++) accS[m_][n_] = Z4;                     \
  }                                                                            \
} while (0)

#define MFMA_ALL(AF) do {                                                      \
  UNRL for (int m_ = 0; m_ < 2; m_++)                                          \
    UNRL for (int n_ = 0; n_ < 4; n_++)                                        \
      accS[m_][n_] = __builtin_amdgcn_mfma_f32_16x16x32_bf16(                  \
          asbf((AF)[m_]), bfv_[n_], accS[m_][n_], 0, 0, 0);                    \
} while (0)

__global__ __launch_bounds__(64, 4)
void k_main(const unsigned short* __restrict__ abf, const float* __restrict__ em,
            float* __restrict__ sim, uint32_t* __restrict__ cand,
            float* __restrict__ sumexp) {
  const int l  = threadIdx.x;
  const int li = l & 15, lg = l >> 4;
  const int rg = blockIdx.x >> 9;        // row-group 0..7 (32 rows each)
  const int cb = blockIdx.x & 511;       // col-block 0..511 (64 cols each)
  const int r0 = rg * WM;
  const int c0 = cb * WN;

  const f32x4 Z4 = {0.f, 0.f, 0.f, 0.f};
  f32x4 accT[2][4], accS[2][4];
  UNRL for (int m = 0; m < 2; m++)
    UNRL for (int n = 0; n < 4; n++) { accT[m][n] = Z4; accS[m][n] = Z4; }

  // per-lane base addresses (A: bf16 row r0+m*16+li; B: f32 row c0+n*16+li)
  const unsigned short* a0 = abf + (size_t)(r0 + li) * NF + lg * 8;
  const float* b0 = em + (size_t)(c0 + li) * NF + lg * 8;

  #pragma unroll 2
  for (int tt = 0; tt < NKSTEP; ++tt) {
    const int k0 = tt * 32;
    u16x8 af_[2];
    UNRL for (int m_ = 0; m_ < 2; m_++)
      af_[m_] = *(const u16x8*)(a0 + (size_t)m_ * 16 * NF + k0);
    bf16x8 bfv_[4];
    UNRL for (int n_ = 0; n_ < 4; n_++) {
      const float* bp_ = b0 + (size_t)n_ * 16 * NF + k0;
      f32x4 x0_ = *(const f32x4*)bp_;
      f32x4 x1_ = *(const f32x4*)(bp_ + 4);
      UNRL for (int e_ = 0; e_ < 4; e_++) bfv_[n_][e_] = (__bf16)x0_[e_];
      UNRL for (int e_ = 0; e_ < 4; e_++) bfv_[n_][4 + e_] = (__bf16)x1_[e_];
    }
    const int s0_ = k0 / SPLITW, s1_ = (k0 + 31) / SPLITW;
    if (s1_ > s0_) {                    // split boundary inside step (9/64)
      const int thr_ = s1_ * SPLITW - k0;   // 1..31
      u16x8 am_[2];
      UNRL for (int m_ = 0; m_ < 2; m_++)
        UNRL for (int e_ = 0; e_ < 8; e_++)
          am_[m_][e_] = (lg * 8 + e_) < thr_ ? af_[m_][e_] : (unsigned short)0;
      MFMA_ALL(am_);
      FINALIZE(s0_);
      UNRL for (int m_ = 0; m_ < 2; m_++)
        UNRL for (int e_ = 0; e_ < 8; e_++)
          am_[m_][e_] = (lg * 8 + e_) < thr_ ? (unsigned short)0 : af_[m_][e_];
      MFMA_ALL(am_);
    } else {
      MFMA_ALL(af_);
    }
  }
  FINALIZE(NSPLIT - 1);

  // epilogue: scaled sim write + per-row sumexp partials (|sim|<=20.5)
  UNRL for (int m = 0; m < 2; m++) {
    UNRL for (int j = 0; j < 4; j++) {
      const int rowg = r0 + m * 16 + lg * 4 + j;
      float se = 0.f;
      UNRL for (int n = 0; n < 4; n++) {
        float v = accT[m][n][j] * INV_BETA;
        sim[(size_t)rowg * NC + c0 + n * 16 + li] = v;
        se += __expf(v);
      }
      UNRL for (int d = 1; d < 16; d <<= 1) se += __shfl_xor(se, d);
      if (li == 0) atomicAdd(&sumexp[rowg], se);
    }
  }
}

__device__ __forceinline__ void casd(unsigned long long& a, unsigned long long& b) {
  unsigned long long mx = a > b ? a : b;
  unsigned long long mn = a > b ? b : a;
  a = mx; b = mn;
}

// merge two descending sorted-8 lists -> a = top-8 descending
__device__ __forceinline__ void merge8(unsigned long long* a,
                                       const unsigned long long* b) {
  unsigned long long hi[8];
  UNRL for (int i = 0; i < 8; i++) {
    unsigned long long x = a[i], y = b[7 - i];
    hi[i] = x > y ? x : y;
  }
  casd(hi[0], hi[4]); casd(hi[1], hi[5]); casd(hi[2], hi[6]); casd(hi[3], hi[7]);
  casd(hi[0], hi[2]); casd(hi[1], hi[3]); casd(hi[4], hi[6]); casd(hi[5], hi[7]);
  casd(hi[0], hi[1]); casd(hi[2], hi[3]); casd(hi[4], hi[5]); casd(hi[6], hi[7]);
  UNRL for (int i = 0; i < 8; i++) a[i] = hi[i];
}

// level 1: (split, row, group of 64 col-blocks) -> top-6 of 384 candidates
__global__ __launch_bounds__(64)
void k_m1(const uint32_t* __restrict__ cand,
          unsigned long long* __restrict__ part) {
  const int bx = blockIdx.x;           // 20480 = 10 * 256 * 8
  const int s = bx >> 11;
  const int b = (bx >> 3) & 255;
  const int g = bx & 7;
  const int l = threadIdx.x;

  const uint32_t* src = cand + ((size_t)(s * NB + b) * NBLK + g * 64) * 6;
  unsigned long long t8[8];
  UNRL for (int i = 0; i < 8; i++) t8[i] = 0ull;

  UNRL for (int i = 0; i < 6; i++) {
    const int idx = l + i * 64;                       // 0..383, coalesced
    const uint32_t e = src[idx];
    const uint32_t colg = (uint32_t)(g * 64 + idx / 6) * 64u + (e & 63u);
    unsigned long long v = ((unsigned long long)(e & 0xFFFFFF80u) << 32)
                         | (unsigned long long)(0xFFFFu ^ colg);
    UNRL for (int k = 0; k < 8; k++) {
      if (v > t8[k]) { unsigned long long tmp = t8[k]; t8[k] = v; v = tmp; }
    }
  }
  UNRL for (int d = 1; d < 64; d <<= 1) {
    unsigned long long o[8];
    UNRL for (int i = 0; i < 8; i++) o[i] = __shfl_xor(t8[i], d);
    merge8(t8, o);
  }
  if (l == 0) {
    unsigned long long* dst = part + ((size_t)(s * NB + b) * 8 + g) * 6;
    UNRL for (int r = 0; r < 6; r++) dst[r] = t8[r];
  }
}

// level 2: merge 48 survivors, gather logp from sim, accumulate loss
__global__ __launch_bounds__(64)
void k_m2(const unsigned long long* __restrict__ part,
          const float* __restrict__ sim, const float* __restrict__ sumexp,
          const int* __restrict__ tgt, float* __restrict__ out) {
  const int s = blockIdx.x >> 8;
  const int b = blockIdx.x & 255;
  const int l = threadIdx.x;

  unsigned long long t8[8];
  UNRL for (int i = 0; i < 8; i++) t8[i] = 0ull;
  t8[0] = (l < 48) ? part[(size_t)(s * NB + b) * 48 + l] : 0ull;

  UNRL for (int d = 1; d < 64; d <<= 1) {
    unsigned long long o[8];
    UNRL for (int i = 0; i < 8; i++) o[i] = __shfl_xor(t8[i], d);
    merge8(t8, o);
  }
  if (l == 0) {
    const int tg = tgt[b];
    const float lz = logf(sumexp[b]);
    float acc = 0.f; int cnt = 0;
    UNRL for (int r = 0; r < 6; r++) {
      const int col = (int)(((unsigned)(t8[r] & 0xFFFFull)) ^ 0xFFFFu);
      if (col != tg) { acc += sim[(size_t)b * NC + col]; cnt++; }
    }
    const float simt = sim[(size_t)b * NC + tg];
    const float contrib = (simt - lz) + (acc - (float)cnt * lz) * (1.0f / 6.0f);
    atomicAdd(out, -contrib * (1.0f / (NSPLIT * NB)));
  }
}

extern "C" void kernel_launch(void* const* d_in, const int* in_sizes, int n_in,
                              void* d_out, int out_size, void* d_ws, size_t ws_size,
                              hipStream_t stream) {
  const float* inp = (const float*)d_in[0];
  const float* em  = (const float*)d_in[1];
  const int*   tgt = (const int*)d_in[2];
  float* out = (float*)d_out;

  char* ws = (char*)d_ws;
  float* sim = (float*)ws;                                          // 32 MB
  size_t off = (size_t)NB * NC * 4;
  uint32_t* cand = (uint32_t*)(ws + off);                           // 30 MB
  off += (size_t)NSPLIT * NB * NBLK * 6 * 4;
  unsigned long long* part = (unsigned long long*)(ws + off);       // 0.94 MB
  off += (size_t)NSPLIT * NB * 8 * 6 * 8;
  float* sumexp = (float*)(ws + off);
  off += 1024;
  unsigned short* abf = (unsigned short*)(ws + off);                // 1 MB

  k_zero<<<1, 256, 0, stream>>>(sumexp, out);
  k_cvtA<<<256, 256, 0, stream>>>(inp, abf);
  k_main<<<8 * NBLK, 64, 0, stream>>>(abf, em, sim, cand, sumexp);
  k_m1<<<NSPLIT * NB * 8, 64, 0, stream>>>(cand, part);
  k_m2<<<NSPLIT * NB, 64, 0, stream>>>(part, sim, sumexp, tgt, out);
}